// Round 12
// baseline (526.399 us; speedup 1.0000x reference)
//
#include <hip/hip_runtime.h>
#include <stdint.h>

#define USER_NUM 100000
#define ITEM_NUM 200000
#define N_NODES  300000
#define EMB      64
#define NNZ      2000000
#define BATCH    4096
#define R1M      1000000u        // NNZ/2, threefry pair offset for edge dropout
#define HALF_MSG 9600000u        // N_NODES*EMB/2, pair offset for msg dropout
#define HALF_N   150000          // node pairing offset = HALF_MSG/64
#define INVK     1.1111111111111112f  // 1/0.9

#define NBK2     256             // coarse buckets (pass A)
#define BROWS    1172            // rows per bucket (even!); 256*1172 = 300032
#define BCAP2    7680            // entries per bucket (mean 7032, +7.7 sigma)
#define ABLK     480             // pass-A blocks
#define PCH      2084            // threefry PAIRS per pass-A block (480*2084 >= 1M)
#define LDSCAP   3968            // LDS staging (kept mean 3751, +11 sigma)

typedef short short8 __attribute__((ext_vector_type(8)));
typedef float f32x4  __attribute__((ext_vector_type(4)));

#if defined(__has_builtin)
# if __has_builtin(__builtin_amdgcn_cvt_f32_fp8)
#  define HAS_CVT_FP8 1
# endif
#endif

// ---------------- threefry2x32 (exact JAX replica) ----------------
__host__ __device__ inline uint32_t rotl32(uint32_t v, int r) {
    return (v << r) | (v >> (32 - r));
}

__host__ __device__ inline void threefry2x32(uint32_t k0, uint32_t k1,
                                             uint32_t x0, uint32_t x1,
                                             uint32_t& o0, uint32_t& o1) {
    uint32_t k2 = k0 ^ k1 ^ 0x1BD11BDAu;
    x0 += k0; x1 += k1;
#define TF_R(r) { x0 += x1; x1 = rotl32(x1, r); x1 ^= x0; }
    TF_R(13) TF_R(15) TF_R(26) TF_R(6)
    x0 += k1; x1 += k2 + 1u;
    TF_R(17) TF_R(29) TF_R(16) TF_R(24)
    x0 += k2; x1 += k0 + 2u;
    TF_R(13) TF_R(15) TF_R(26) TF_R(6)
    x0 += k0; x1 += k1 + 3u;
    TF_R(17) TF_R(29) TF_R(16) TF_R(24)
    x0 += k1; x1 += k2 + 4u;
    TF_R(13) TF_R(15) TF_R(26) TF_R(6)
    x0 += k2; x1 += k0 + 5u;
#undef TF_R
    o0 = x0; o1 = x1;
}

__host__ __device__ inline float tf_uniform(uint32_t bits) {
    uint32_t fb = (bits >> 9) | 0x3f800000u;
    return __builtin_bit_cast(float, fb) - 1.0f;
}

// ---------------- bf16 helpers ----------------
__device__ inline float bf2f(uint16_t u) {
    uint32_t x = ((uint32_t)u) << 16;
    return __builtin_bit_cast(float, x);
}
__device__ inline uint16_t f2bf(float f) {   // round-to-nearest-even
    uint32_t x = __builtin_bit_cast(uint32_t, f);
    uint32_t r = (x + 0x7FFFu + ((x >> 16) & 1u)) >> 16;
    return (uint16_t)r;
}

// ---------------- fp8 e4m3fn (OCP) helpers ----------------
// decode: HW v_cvt_f32_fp8 when available; manual fallback
__device__ inline float fp82f(uint32_t b) {
#ifdef HAS_CVT_FP8
    return __builtin_amdgcn_cvt_f32_fp8(b, 0);
#else
    uint32_t E = (b >> 3) & 15u, m = b & 7u;
    float mag = E ? __builtin_bit_cast(float, ((E + 120u) << 23) | (m << 20))
                  : (float)m * 0.001953125f;   // denorm step 2^-9
    return (b & 0x80u) ? -mag : mag;
#endif
}

// encode: manual RNE (deterministic, OCP e4m3fn)
__device__ inline uint32_t f2fp8(float f) {
    uint32_t u = __builtin_bit_cast(uint32_t, f);
    uint32_t s = (u >> 31) << 7;
    uint32_t a = u & 0x7fffffffu;
    if (a >= 0x3C800000u) {                  // >= 2^-6 : normal range
        uint32_t m = a & 0x7fffffu;
        uint32_t r = (m + 0x7FFFFu + ((m >> 20) & 1u)) >> 20;  // RNE -> 3 bits
        uint32_t E = (a >> 23) - 120u;       // e4m3 biased exp
        if (r == 8u) { r = 0u; E += 1u; }
        if (E > 15u || (E == 15u && r == 7u)) return s | 0x7Eu;  // clamp 448
        return s | (E << 3) | r;
    }
    if (a <= 0x3A800000u) return s;          // < ~2^-10 -> 0
    // denorm: m3 = RNE(value * 2^9)
    uint32_t e8 = a >> 23;                   // 117..120
    uint32_t M = (a & 0x7fffffu) | 0x800000u;
    int sh = 21 - ((int)e8 - 120);           // 21..24
    uint32_t half = 1u << (sh - 1);
    uint32_t m3 = (M + half - 1u + ((M >> sh) & 1u)) >> sh;
    if (m3 >= 8u) return s | 0x08u;
    return s | m3;
}

// ---------------- ego init: concat(uemb,iemb) -> bf16 + fp8 ----------------
__global__ __launch_bounds__(256) void k_conv(const float* __restrict__ u,
                                              const float* __restrict__ it,
                                              uint16_t* __restrict__ dst,
                                              uint8_t* __restrict__ dst8) {
    int i = blockIdx.x * 256 + threadIdx.x;     // quad index
    const int TOT = N_NODES * EMB / 4;          // 4.8M
    if (i >= TOT) return;
    const int UQ = USER_NUM * EMB / 4;
    float4 f = (i < UQ) ? ((const float4*)u)[i] : ((const float4*)it)[i - UQ];
    ushort4 o;
    o.x = f2bf(f.x); o.y = f2bf(f.y); o.z = f2bf(f.z); o.w = f2bf(f.w);
    ((ushort4*)dst)[i] = o;
    uint32_t p = f2fp8(f.x) | (f2fp8(f.y) << 8) | (f2fp8(f.z) << 16) | (f2fp8(f.w) << 24);
    ((uint32_t*)dst8)[i] = p;
}

// ---------------- sort pass A: LDS-binned coarse bucket sort ---------------
// One threefry per (t, t+1M) pair serves two edges.
__global__ __launch_bounds__(256) void k_sortA(const int* __restrict__ erow,
                                               const int* __restrict__ ecol,
                                               const float* __restrict__ evals,
                                               uint32_t* __restrict__ bcnt,
                                               uint2* __restrict__ tmp,
                                               uint32_t kn0, uint32_t kn1) {
    __shared__ uint32_t hist[NBK2];
    __shared__ uint32_t lstart[NBK2];
    __shared__ uint32_t gbase[NBK2];
    __shared__ uint32_t cur[NBK2];
    __shared__ uint32_t eidx[LDSCAP];
    __shared__ uint8_t  keepb[PCH];
    int tid = threadIdx.x;
    uint32_t pbase = (uint32_t)blockIdx.x * PCH;
    hist[tid] = 0u;
    __syncthreads();
    // phase 1: one threefry per pair, histogram both edges
    for (int j = tid; j < PCH; j += 256) {
        uint32_t t = pbase + (uint32_t)j;
        uint8_t kb = 0u;
        if (t < R1M) {
            uint32_t o0, o1;
            threefry2x32(kn0, kn1, t, t + R1M, o0, o1);
            bool k0 = tf_uniform(o0) < 0.9f;
            bool k1 = tf_uniform(o1) < 0.9f;
            kb = (uint8_t)((k0 ? 1u : 0u) | (k1 ? 2u : 0u));
            if (k0) atomicAdd(&hist[(uint32_t)erow[t] / BROWS], 1u);
            if (k1) atomicAdd(&hist[(uint32_t)erow[t + R1M] / BROWS], 1u);
        }
        keepb[j] = kb;
    }
    __syncthreads();
    uint32_t x = hist[tid];
    lstart[tid] = x;
    __syncthreads();
    for (int off = 1; off < 256; off <<= 1) {
        uint32_t y = (tid >= off) ? lstart[tid - off] : 0u;
        __syncthreads();
        lstart[tid] += y;
        __syncthreads();
    }
    uint32_t exc = lstart[tid] - x;
    uint32_t gb = 0u;
    if (x) gb = atomicAdd(&bcnt[tid], x);
    lstart[tid] = exc;
    gbase[tid] = gb;
    cur[tid] = exc;
    __syncthreads();
    // phase 2: scatter kept edge ids into LDS, bucket-sorted
    for (int j = tid; j < PCH; j += 256) {
        uint8_t kb = keepb[j];
        if (!kb) continue;
        uint32_t t = pbase + (uint32_t)j;
        if (kb & 1u) {
            uint32_t b = (uint32_t)erow[t] / BROWS;
            uint32_t p = atomicAdd(&cur[b], 1u);
            if (p < LDSCAP) eidx[p] = t;
        }
        if (kb & 2u) {
            uint32_t e2 = t + R1M;
            uint32_t b = (uint32_t)erow[e2] / BROWS;
            uint32_t p = atomicAdd(&cur[b], 1u);
            if (p < LDSCAP) eidx[p] = e2;
        }
    }
    __syncthreads();
    uint32_t total = min(lstart[NBK2 - 1] + hist[NBK2 - 1], (uint32_t)LDSCAP);
    // phase 3: coalesced group write-out
    for (uint32_t p = tid; p < total; p += 256) {
        uint32_t e = eidx[p];
        uint32_t row = (uint32_t)erow[e];
        uint32_t b = row / BROWS;
        uint32_t off = gbase[b] + (p - lstart[b]);
        if (off < BCAP2) {
            uint2 q;
            q.x = (uint32_t)ecol[e] | ((row - b * BROWS) << 19);
            q.y = __builtin_bit_cast(uint32_t, evals[e] * INVK);
            tmp[(size_t)b * BCAP2 + off] = q;
        }
    }
}

// ---------------- sort pass B: within-bucket row sort ----------------------
__global__ __launch_bounds__(256) void k_sortB(const uint2* __restrict__ tmp,
                                               const uint32_t* __restrict__ bcnt,
                                               uint2* __restrict__ cv,
                                               uint32_t* __restrict__ rowstart,
                                               uint32_t* __restrict__ rowend) {
    __shared__ uint32_t hist[1280];
    __shared__ uint32_t tsum[256];
    int b = blockIdx.x;
    int t = threadIdx.x;
    uint32_t cnt = min(bcnt[b], (uint32_t)BCAP2);
    for (int i = t; i < 1280; i += 256) hist[i] = 0u;
    __syncthreads();
    const uint2* src = tmp + (size_t)b * BCAP2;
    for (uint32_t i = t; i < cnt; i += 256)
        atomicAdd(&hist[src[i].x >> 19], 1u);
    __syncthreads();
    uint32_t l[5];
    uint32_t s = 0u;
#pragma unroll
    for (int i = 0; i < 5; ++i) { l[i] = hist[t * 5 + i]; s += l[i]; }
    tsum[t] = s;
    __syncthreads();
    for (int off = 1; off < 256; off <<= 1) {
        uint32_t y = (t >= off) ? tsum[t - off] : 0u;
        __syncthreads();
        tsum[t] += y;
        __syncthreads();
    }
    uint32_t run = tsum[t] - s;
    uint32_t cvb = (uint32_t)b * BCAP2;
#pragma unroll
    for (int i = 0; i < 5; ++i) {
        uint32_t e0 = run;
        run += l[i];
        int idx = t * 5 + i;
        int row = b * BROWS + idx;
        if (idx < BROWS && row < N_NODES) {
            rowstart[row] = cvb + e0;
            rowend[row]   = cvb + run;
        }
        hist[idx] = e0;
    }
    __syncthreads();
    for (uint32_t i = t; i < cnt; i += 256) {
        uint2 p = src[i];
        uint32_t rl = p.x >> 19;
        uint32_t pos = atomicAdd(&hist[rl], 1u);
        uint2 q;
        q.x = p.x & 0x7FFFFu;
        q.y = p.y;
        cv[(size_t)cvb + pos] = q;
    }
}

// -------- SPMV: 2 adjacent rows per wave, fp8 gather, 8-deep bursts -------
__global__ __launch_bounds__(256) void k_spmv(const uint8_t* __restrict__ ego8,
                                              uint16_t* __restrict__ side,
                                              const uint32_t* __restrict__ rowstart,
                                              const uint32_t* __restrict__ rowend,
                                              const uint2* __restrict__ cv) {
    int lane = threadIdx.x & 63;
    int wv = __builtin_amdgcn_readfirstlane((int)((blockIdx.x * 256 + threadIdx.x) >> 6));
    int nw = (gridDim.x * 256) >> 6;
    for (int n0 = wv * 2; n0 < N_NODES; n0 += nw * 2) {
        uint32_t st  = __builtin_amdgcn_readfirstlane(rowstart[n0]);
        uint32_t mid = __builtin_amdgcn_readfirstlane(rowend[n0]);
        uint32_t en  = __builtin_amdgcn_readfirstlane(rowend[n0 + 1]);
        float acc0 = 0.0f, acc1 = 0.0f;
        for (uint32_t j0 = st; j0 < en; j0 += 8) {
            uint32_t cx[8];
            float v0[8], v1[8];
#pragma unroll
            for (int u = 0; u < 8; ++u) {
                uint2 p = cv[j0 + u];            // uniform addr -> scalar load
                uint32_t idx = j0 + (uint32_t)u;
                bool ok = idx < en;
                bool r1 = idx >= mid;
                cx[u] = ok ? p.x : 0u;
                float v = ok ? __builtin_bit_cast(float, p.y) : 0.0f;
                v0[u] = r1 ? 0.0f : v;           // uniform selects (SALU)
                v1[u] = r1 ? v : 0.0f;
            }
            float g[8];
#pragma unroll
            for (int u = 0; u < 8; ++u)
                g[u] = fp82f((uint32_t)ego8[(size_t)cx[u] * 64u + (uint32_t)lane]);
#pragma unroll
            for (int u = 0; u < 8; ++u) {
                acc0 = fmaf(v0[u], g[u], acc0);
                acc1 = fmaf(v1[u], g[u], acc1);
            }
        }
        side[(size_t)n0 * 64 + lane] = f2bf(acc0);
        side[(size_t)(n0 + 1) * 64 + lane] = f2bf(acc1);
    }
}

// -------- elementwise bf16 product frag: (side ∘ ego) --------
__device__ inline short8 mul_frag(short8 s, uint4 e) {
    uint32_t ew[4] = {e.x, e.y, e.z, e.w};
    short8 r;
#pragma unroll
    for (int i = 0; i < 4; ++i) {
        float a0 = bf2f((uint16_t)s[2 * i])     * bf2f((uint16_t)(ew[i] & 0xffffu));
        float a1 = bf2f((uint16_t)s[2 * i + 1]) * bf2f((uint16_t)(ew[i] >> 16));
        r[2 * i]     = (short)f2bf(a0);
        r[2 * i + 1] = (short)f2bf(a1);
    }
    return r;
}

// -------- dense via MFMA: [s | ego*s] (Nx128) @ [Wg;Wb] (128x64), in-place --
// Writes both bf16 ego (dense/segacc) and fp8 ego (next layer's gather).
__global__ __launch_bounds__(256) void k_dense_mfma(
        uint16_t* __restrict__ ego, uint8_t* __restrict__ ego8,
        const uint16_t* __restrict__ side,
        const float* __restrict__ Wg, const float* __restrict__ bg,
        const float* __restrict__ Wb, const float* __restrict__ bb,
        uint32_t km0, uint32_t km1) {
    int lane = threadIdx.x & 63;
    int wave = (blockIdx.x * 256 + threadIdx.x) >> 6;
    int nw = (gridDim.x * 256) >> 6;
    int m = lane & 15;     // A row within tile / C col within tile
    int g = lane >> 4;     // k-group (A) / row-group (C)

    short8 bfr[4][4];
#pragma unroll
    for (int kk = 0; kk < 4; ++kk) {
        const float* W = (kk < 2) ? Wg : Wb;
        int krow = (kk & 1) * 32 + 8 * g;
#pragma unroll
        for (int nt = 0; nt < 4; ++nt) {
#pragma unroll
            for (int i = 0; i < 8; ++i)
                bfr[kk][nt][i] = (short)f2bf(W[(krow + i) * 64 + 16 * nt + m]);
        }
    }
    float bias[4];
#pragma unroll
    for (int nt = 0; nt < 4; ++nt)
        bias[nt] = bg[16 * nt + m] + bb[16 * nt + m];

    for (int tile = wave; tile < HALF_N / 16; tile += nw) {
        int n0 = tile * 16;
        uint32_t keepB = 0;
        {
            const uint16_t* srow = side + (size_t)(n0 + m) * 64;
            const uint16_t* erw  = ego  + (size_t)(n0 + m) * 64;
            short8 a0 = *(const short8*)(srow + 8 * g);
            short8 a1 = *(const short8*)(srow + 32 + 8 * g);
            uint4  e0 = *(const uint4*)(erw + 8 * g);
            uint4  e1 = *(const uint4*)(erw + 32 + 8 * g);
            short8 a2 = mul_frag(a0, e0);
            short8 a3 = mul_frag(a1, e1);
            f32x4 acc[4];
#pragma unroll
            for (int nt = 0; nt < 4; ++nt) {
                acc[nt] = (f32x4)(0.0f);
                acc[nt] = __builtin_amdgcn_mfma_f32_16x16x32_bf16(a0, bfr[0][nt], acc[nt], 0, 0, 0);
                acc[nt] = __builtin_amdgcn_mfma_f32_16x16x32_bf16(a1, bfr[1][nt], acc[nt], 0, 0, 0);
                acc[nt] = __builtin_amdgcn_mfma_f32_16x16x32_bf16(a2, bfr[2][nt], acc[nt], 0, 0, 0);
                acc[nt] = __builtin_amdgcn_mfma_f32_16x16x32_bf16(a3, bfr[3][nt], acc[nt], 0, 0, 0);
            }
#pragma unroll
            for (int nt = 0; nt < 4; ++nt) {
#pragma unroll
                for (int i = 0; i < 4; ++i) {
                    int row = n0 + g * 4 + i;
                    int col = 16 * nt + m;
                    float h = acc[nt][i] + bias[nt];
                    h = (h >= 0.0f) ? h : 0.2f * h;
                    uint32_t j = (uint32_t)row * 64u + (uint32_t)col;
                    uint32_t o0, o1;
                    threefry2x32(km0, km1, j, j + HALF_MSG, o0, o1);
                    bool kA = tf_uniform(o0) < 0.9f;
                    keepB |= (uint32_t)(tf_uniform(o1) < 0.9f) << (nt * 4 + i);
                    float val = kA ? h * INVK : 0.0f;
                    ego[(size_t)row * 64 + col] = f2bf(val);
                    ego8[(size_t)row * 64 + col] = (uint8_t)f2fp8(val);
                }
            }
        }
        {
            int R = n0 + HALF_N;
            const uint16_t* srow = side + (size_t)(R + m) * 64;
            const uint16_t* erw  = ego  + (size_t)(R + m) * 64;
            short8 a0 = *(const short8*)(srow + 8 * g);
            short8 a1 = *(const short8*)(srow + 32 + 8 * g);
            uint4  e0 = *(const uint4*)(erw + 8 * g);
            uint4  e1 = *(const uint4*)(erw + 32 + 8 * g);
            short8 a2 = mul_frag(a0, e0);
            short8 a3 = mul_frag(a1, e1);
            f32x4 acc[4];
#pragma unroll
            for (int nt = 0; nt < 4; ++nt) {
                acc[nt] = (f32x4)(0.0f);
                acc[nt] = __builtin_amdgcn_mfma_f32_16x16x32_bf16(a0, bfr[0][nt], acc[nt], 0, 0, 0);
                acc[nt] = __builtin_amdgcn_mfma_f32_16x16x32_bf16(a1, bfr[1][nt], acc[nt], 0, 0, 0);
                acc[nt] = __builtin_amdgcn_mfma_f32_16x16x32_bf16(a2, bfr[2][nt], acc[nt], 0, 0, 0);
                acc[nt] = __builtin_amdgcn_mfma_f32_16x16x32_bf16(a3, bfr[3][nt], acc[nt], 0, 0, 0);
            }
#pragma unroll
            for (int nt = 0; nt < 4; ++nt) {
#pragma unroll
                for (int i = 0; i < 4; ++i) {
                    int row = R + g * 4 + i;
                    int col = 16 * nt + m;
                    float h = acc[nt][i] + bias[nt];
                    h = (h >= 0.0f) ? h : 0.2f * h;
                    bool kB = (keepB >> (nt * 4 + i)) & 1u;
                    float val = kB ? h * INVK : 0.0f;
                    ego[(size_t)row * 64 + col] = f2bf(val);
                    ego8[(size_t)row * 64 + col] = (uint8_t)f2fp8(val);
                }
            }
        }
    }
}

// ---------------- batch accumulation & finalize ----------------
__device__ inline float wred64(float v) {
#pragma unroll
    for (int m = 32; m >= 1; m >>= 1) v += __shfl_xor(v, m, 64);
    return v;
}

__global__ __launch_bounds__(256) void k_segacc(const void* __restrict__ ua_,
                                                const void* __restrict__ ia_,
                                                const int* __restrict__ uid,
                                                const int* __restrict__ iid,
                                                const int* __restrict__ nid,
                                                float* __restrict__ dotp,
                                                float* __restrict__ dotn,
                                                float* __restrict__ sqs,
                                                int normalize, int f32) {
    int gt = blockIdx.x * 256 + threadIdx.x;
    int w = gt >> 6, lane = gt & 63;
    if (w >= BATCH) return;
    int u = uid[w], p = iid[w], n = nid[w];
    float eu, ep, en;
    if (f32) {
        const float* ua = (const float*)ua_;
        const float* ia = (const float*)ia_;
        eu = ua[(size_t)u * EMB + lane];
        ep = ia[(size_t)p * EMB + lane];
        en = ia[(size_t)n * EMB + lane];
    } else {
        const uint16_t* ua = (const uint16_t*)ua_;
        const uint16_t* ia = (const uint16_t*)ia_;
        eu = bf2f(ua[(size_t)u * EMB + lane]);
        ep = bf2f(ia[(size_t)p * EMB + lane]);
        en = bf2f(ia[(size_t)n * EMB + lane]);
    }
    if (normalize) {
        float su = wred64(eu * eu);
        float sp = wred64(ep * ep);
        float sn = wred64(en * en);
        eu /= fmaxf(sqrtf(su), 1e-12f);
        ep /= fmaxf(sqrtf(sp), 1e-12f);
        en /= fmaxf(sqrtf(sn), 1e-12f);
    }
    float dp = wred64(eu * ep);
    float dn = wred64(eu * en);
    float s3 = wred64(eu * eu + ep * ep + en * en);
    if (lane == 0) {
        dotp[w] += dp;
        dotn[w] += dn;
        sqs[w]  += s3;
    }
}

__global__ __launch_bounds__(256) void k_finalize(const float* __restrict__ dotp,
                                                  const float* __restrict__ dotn,
                                                  const float* __restrict__ sqs,
                                                  float* __restrict__ out) {
    __shared__ float smf[256], ssq[256];
    int t = threadIdx.x;
    float mf = 0.0f, s = 0.0f;
    for (int b = t; b < BATCH; b += 256) {
        float x = dotp[b] - dotn[b];
        float ls = fminf(x, 0.0f) - log1pf(expf(-fabsf(x)));
        mf += ls;
        s += sqs[b];
    }
    smf[t] = mf; ssq[t] = s;
    __syncthreads();
    for (int off = 128; off > 0; off >>= 1) {
        if (t < off) { smf[t] += smf[t + off]; ssq[t] += ssq[t + off]; }
        __syncthreads();
    }
    if (t == 0) {
        float mf_loss = -smf[0] / (float)BATCH;
        float reg = 0.5f * ssq[0];
        float emb_loss = (float)1e-4 * reg / (float)BATCH;
        out[0] = mf_loss + emb_loss;
        out[1] = mf_loss;
        out[2] = emb_loss;
    }
}

// ---------------- launch ----------------
extern "C" void kernel_launch(void* const* d_in, const int* in_sizes, int n_in,
                              void* d_out, int out_size, void* d_ws, size_t ws_size,
                              hipStream_t stream) {
    const int*   erow  = (const int*)d_in[0];
    const int*   ecol  = (const int*)d_in[1];
    const float* evals = (const float*)d_in[2];
    const float* uemb  = (const float*)d_in[3];
    const float* iemb  = (const float*)d_in[4];
    const int*   uid   = (const int*)d_in[5];
    const int*   iid   = (const int*)d_in[6];
    const int*   nid   = (const int*)d_in[7];
    const float* Wg[3] = {(const float*)d_in[8],  (const float*)d_in[12], (const float*)d_in[16]};
    const float* bg[3] = {(const float*)d_in[9],  (const float*)d_in[13], (const float*)d_in[17]};
    const float* Wb[3] = {(const float*)d_in[10], (const float*)d_in[14], (const float*)d_in[18]};
    const float* bb[3] = {(const float*)d_in[11], (const float*)d_in[15], (const float*)d_in[19]};

    // workspace layout (~130 MB)
    const size_t NBE = (size_t)NBK2 * BCAP2;                        // 1,966,080
    uint2*    tmp      = (uint2*)d_ws;                              // 15.7 MB
    uint2*    cv       = tmp + NBE;                                 // 15.7 MB (+8 pad)
    uint16_t* side     = (uint16_t*)(cv + NBE + 8);                 // 38.4 MB
    uint16_t* ego      = side + (size_t)N_NODES * EMB;              // 38.4 MB
    uint8_t*  ego8     = (uint8_t*)(ego + (size_t)N_NODES * EMB);   // 19.2 MB
    uint32_t* rowstart = (uint32_t*)(ego8 + (size_t)N_NODES * EMB); // 1.2 MB
    uint32_t* rowend   = rowstart + N_NODES;                        // 1.2 MB
    uint32_t* bcnt     = rowend + N_NODES;                          // 1 KB
    float*    dotp     = (float*)(bcnt + NBK2);                     // 16 KB
    float*    dotn     = dotp + BATCH;
    float*    sqs      = dotn + BATCH;
    size_t needed = (NBE * 2 + 8) * 8 + (size_t)N_NODES * EMB * (2 * 2 + 1)
                  + ((size_t)2 * N_NODES + NBK2 + 3 * BATCH) * 4;
    if (ws_size < needed) return;

    // host-side JAX key derivation: key(42) = (0,42)
    uint32_t a0, b0, a1, b1;
    threefry2x32(0u, 42u, 0u, 2u, a0, b0);   // split block 0
    threefry2x32(0u, 42u, 1u, 3u, a1, b1);   // split block 1
    uint32_t knode0 = a0, knode1 = a1;       // k_node
    uint32_t kmsg0  = b0, kmsg1  = b1;       // k_msg
    uint32_t mk[6];
    for (uint32_t k = 0; k < 3; ++k)
        threefry2x32(kmsg0, kmsg1, 0u, k, mk[2 * k], mk[2 * k + 1]);

    hipMemsetAsync(bcnt, 0, (size_t)NBK2 * 4, stream);
    hipMemsetAsync(dotp, 0, 3 * BATCH * 4, stream);

    // ego (bf16 + fp8) init + two-pass LDS-binned CSR build
    k_conv<<<(N_NODES * EMB / 4 + 255) / 256, 256, 0, stream>>>(uemb, iemb, ego, ego8);
    k_sortA<<<ABLK, 256, 0, stream>>>(erow, ecol, evals, bcnt, tmp, knode0, knode1);
    k_sortB<<<NBK2, 256, 0, stream>>>(tmp, bcnt, cv, rowstart, rowend);

    // segment 0: raw initial embeddings (fp32, exact)
    k_segacc<<<BATCH * 64 / 256, 256, 0, stream>>>(uemb, iemb, uid, iid, nid,
                                                   dotp, dotn, sqs, 0, 1);

    for (int k = 0; k < 3; ++k) {
        k_spmv<<<2048, 256, 0, stream>>>(ego8, side, rowstart, rowend, cv);
        k_dense_mfma<<<768, 256, 0, stream>>>(ego, ego8, side, Wg[k], bg[k], Wb[k], bb[k],
                                              mk[2 * k], mk[2 * k + 1]);
        k_segacc<<<BATCH * 64 / 256, 256, 0, stream>>>(ego, ego + (size_t)USER_NUM * EMB,
                                                       uid, iid, nid, dotp, dotn, sqs, 1, 0);
    }
    k_finalize<<<1, 256, 0, stream>>>(dotp, dotn, sqs, (float*)d_out);
}

// Round 13
// 480.492 us; speedup vs baseline: 1.0955x; 1.0955x over previous
//
#include <hip/hip_runtime.h>
#include <stdint.h>

#define USER_NUM 100000
#define ITEM_NUM 200000
#define N_NODES  300000
#define EMB      64
#define NNZ      2000000
#define BATCH    4096
#define R1M      1000000u        // NNZ/2, threefry pair offset for edge dropout
#define HALF_MSG 9600000u        // N_NODES*EMB/2, pair offset for msg dropout
#define HALF_N   150000          // node pairing offset = HALF_MSG/64
#define INVK     1.1111111111111112f  // 1/0.9

#define NBK2     256             // coarse buckets (pass A)
#define BROWS    1172            // rows per bucket (even!); 256*1172 = 300032
#define BCAP2    7680            // entries per bucket (mean 7032, +7.7 sigma)
#define ABLK     480             // pass-A blocks
#define PCH      2084            // threefry PAIRS per pass-A block (480*2084 >= 1M)
#define LDSCAP   3968            // LDS staging (kept mean 3751, +11 sigma)

typedef short short8 __attribute__((ext_vector_type(8)));
typedef float f32x4  __attribute__((ext_vector_type(4)));

#if defined(__has_builtin)
# if __has_builtin(__builtin_amdgcn_cvt_f32_fp8)
#  define HAS_CVT_FP8 1
# endif
# if __has_builtin(__builtin_amdgcn_cvt_pk_fp8_f32)
#  define HAS_CVT_PK_FP8 1
# endif
#endif

// ---------------- threefry2x32 (exact JAX replica) ----------------
__host__ __device__ inline uint32_t rotl32(uint32_t v, int r) {
    return (v << r) | (v >> (32 - r));
}

__host__ __device__ inline void threefry2x32(uint32_t k0, uint32_t k1,
                                             uint32_t x0, uint32_t x1,
                                             uint32_t& o0, uint32_t& o1) {
    uint32_t k2 = k0 ^ k1 ^ 0x1BD11BDAu;
    x0 += k0; x1 += k1;
#define TF_R(r) { x0 += x1; x1 = rotl32(x1, r); x1 ^= x0; }
    TF_R(13) TF_R(15) TF_R(26) TF_R(6)
    x0 += k1; x1 += k2 + 1u;
    TF_R(17) TF_R(29) TF_R(16) TF_R(24)
    x0 += k2; x1 += k0 + 2u;
    TF_R(13) TF_R(15) TF_R(26) TF_R(6)
    x0 += k0; x1 += k1 + 3u;
    TF_R(17) TF_R(29) TF_R(16) TF_R(24)
    x0 += k1; x1 += k2 + 4u;
    TF_R(13) TF_R(15) TF_R(26) TF_R(6)
    x0 += k2; x1 += k0 + 5u;
#undef TF_R
    o0 = x0; o1 = x1;
}

__host__ __device__ inline float tf_uniform(uint32_t bits) {
    uint32_t fb = (bits >> 9) | 0x3f800000u;
    return __builtin_bit_cast(float, fb) - 1.0f;
}

// ---------------- bf16 helpers ----------------
__device__ inline float bf2f(uint16_t u) {
    uint32_t x = ((uint32_t)u) << 16;
    return __builtin_bit_cast(float, x);
}
__device__ inline uint16_t f2bf(float f) {   // round-to-nearest-even
    uint32_t x = __builtin_bit_cast(uint32_t, f);
    uint32_t r = (x + 0x7FFFu + ((x >> 16) & 1u)) >> 16;
    return (uint16_t)r;
}

// ---------------- fp8 e4m3fn (OCP) helpers ----------------
__device__ inline float fp82f(uint32_t b) {
#ifdef HAS_CVT_FP8
    return __builtin_amdgcn_cvt_f32_fp8(b, 0);
#else
    uint32_t E = (b >> 3) & 15u, m = b & 7u;
    float mag = E ? __builtin_bit_cast(float, ((E + 120u) << 23) | (m << 20))
                  : (float)m * 0.001953125f;   // denorm step 2^-9
    return (b & 0x80u) ? -mag : mag;
#endif
}

// manual RNE encode (fallback / k_conv)
__device__ inline uint32_t f2fp8(float f) {
    uint32_t u = __builtin_bit_cast(uint32_t, f);
    uint32_t s = (u >> 31) << 7;
    uint32_t a = u & 0x7fffffffu;
    if (a >= 0x3C800000u) {                  // >= 2^-6 : normal range
        uint32_t m = a & 0x7fffffu;
        uint32_t r = (m + 0x7FFFFu + ((m >> 20) & 1u)) >> 20;  // RNE -> 3 bits
        uint32_t E = (a >> 23) - 120u;
        if (r == 8u) { r = 0u; E += 1u; }
        if (E > 15u || (E == 15u && r == 7u)) return s | 0x7Eu;  // clamp 448
        return s | (E << 3) | r;
    }
    if (a <= 0x3A800000u) return s;
    uint32_t e8 = a >> 23;
    uint32_t M = (a & 0x7fffffu) | 0x800000u;
    int sh = 21 - ((int)e8 - 120);
    uint32_t half = 1u << (sh - 1);
    uint32_t m3 = (M + half - 1u + ((M >> sh) & 1u)) >> sh;
    if (m3 >= 8u) return s | 0x08u;
    return s | m3;
}

// pack 4 floats -> 4 fp8 bytes (HW packed cvt when available)
__device__ inline uint32_t pk4_fp8(float f0, float f1, float f2, float f3) {
#ifdef HAS_CVT_PK_FP8
    int r = __builtin_amdgcn_cvt_pk_fp8_f32(f0, f1, 0, false);
    r = __builtin_amdgcn_cvt_pk_fp8_f32(f2, f3, r, true);
    return (uint32_t)r;
#else
    return f2fp8(f0) | (f2fp8(f1) << 8) | (f2fp8(f2) << 16) | (f2fp8(f3) << 24);
#endif
}

// ---------------- ego init: concat(uemb,iemb) -> bf16 + fp8 ----------------
__global__ __launch_bounds__(256) void k_conv(const float* __restrict__ u,
                                              const float* __restrict__ it,
                                              uint16_t* __restrict__ dst,
                                              uint8_t* __restrict__ dst8) {
    int i = blockIdx.x * 256 + threadIdx.x;     // quad index
    const int TOT = N_NODES * EMB / 4;          // 4.8M
    if (i >= TOT) return;
    const int UQ = USER_NUM * EMB / 4;
    float4 f = (i < UQ) ? ((const float4*)u)[i] : ((const float4*)it)[i - UQ];
    ushort4 o;
    o.x = f2bf(f.x); o.y = f2bf(f.y); o.z = f2bf(f.z); o.w = f2bf(f.w);
    ((ushort4*)dst)[i] = o;
    ((uint32_t*)dst8)[i] = pk4_fp8(f.x, f.y, f.z, f.w);
}

// ---------------- repack: bf16 ego -> fp8 ego8 (streaming, coalesced) ------
__global__ __launch_bounds__(256) void k_repack(const uint16_t* __restrict__ ego,
                                                uint8_t* __restrict__ ego8) {
    int i = blockIdx.x * 256 + threadIdx.x;     // 8-elem group
    const int TOT = N_NODES * EMB / 8;          // 2.4M
    if (i >= TOT) return;
    short8 s = ((const short8*)ego)[i];
    uint2 o;
    o.x = pk4_fp8(bf2f((uint16_t)s[0]), bf2f((uint16_t)s[1]),
                  bf2f((uint16_t)s[2]), bf2f((uint16_t)s[3]));
    o.y = pk4_fp8(bf2f((uint16_t)s[4]), bf2f((uint16_t)s[5]),
                  bf2f((uint16_t)s[6]), bf2f((uint16_t)s[7]));
    ((uint2*)ego8)[i] = o;
}

// ---------------- sort pass A: LDS-binned coarse bucket sort ---------------
__global__ __launch_bounds__(256) void k_sortA(const int* __restrict__ erow,
                                               const int* __restrict__ ecol,
                                               const float* __restrict__ evals,
                                               uint32_t* __restrict__ bcnt,
                                               uint2* __restrict__ tmp,
                                               uint32_t kn0, uint32_t kn1) {
    __shared__ uint32_t hist[NBK2];
    __shared__ uint32_t lstart[NBK2];
    __shared__ uint32_t gbase[NBK2];
    __shared__ uint32_t cur[NBK2];
    __shared__ uint32_t eidx[LDSCAP];
    __shared__ uint8_t  keepb[PCH];
    int tid = threadIdx.x;
    uint32_t pbase = (uint32_t)blockIdx.x * PCH;
    hist[tid] = 0u;
    __syncthreads();
    for (int j = tid; j < PCH; j += 256) {
        uint32_t t = pbase + (uint32_t)j;
        uint8_t kb = 0u;
        if (t < R1M) {
            uint32_t o0, o1;
            threefry2x32(kn0, kn1, t, t + R1M, o0, o1);
            bool k0 = tf_uniform(o0) < 0.9f;
            bool k1 = tf_uniform(o1) < 0.9f;
            kb = (uint8_t)((k0 ? 1u : 0u) | (k1 ? 2u : 0u));
            if (k0) atomicAdd(&hist[(uint32_t)erow[t] / BROWS], 1u);
            if (k1) atomicAdd(&hist[(uint32_t)erow[t + R1M] / BROWS], 1u);
        }
        keepb[j] = kb;
    }
    __syncthreads();
    uint32_t x = hist[tid];
    lstart[tid] = x;
    __syncthreads();
    for (int off = 1; off < 256; off <<= 1) {
        uint32_t y = (tid >= off) ? lstart[tid - off] : 0u;
        __syncthreads();
        lstart[tid] += y;
        __syncthreads();
    }
    uint32_t exc = lstart[tid] - x;
    uint32_t gb = 0u;
    if (x) gb = atomicAdd(&bcnt[tid], x);
    lstart[tid] = exc;
    gbase[tid] = gb;
    cur[tid] = exc;
    __syncthreads();
    for (int j = tid; j < PCH; j += 256) {
        uint8_t kb = keepb[j];
        if (!kb) continue;
        uint32_t t = pbase + (uint32_t)j;
        if (kb & 1u) {
            uint32_t b = (uint32_t)erow[t] / BROWS;
            uint32_t p = atomicAdd(&cur[b], 1u);
            if (p < LDSCAP) eidx[p] = t;
        }
        if (kb & 2u) {
            uint32_t e2 = t + R1M;
            uint32_t b = (uint32_t)erow[e2] / BROWS;
            uint32_t p = atomicAdd(&cur[b], 1u);
            if (p < LDSCAP) eidx[p] = e2;
        }
    }
    __syncthreads();
    uint32_t total = min(lstart[NBK2 - 1] + hist[NBK2 - 1], (uint32_t)LDSCAP);
    for (uint32_t p = tid; p < total; p += 256) {
        uint32_t e = eidx[p];
        uint32_t row = (uint32_t)erow[e];
        uint32_t b = row / BROWS;
        uint32_t off = gbase[b] + (p - lstart[b]);
        if (off < BCAP2) {
            uint2 q;
            q.x = (uint32_t)ecol[e] | ((row - b * BROWS) << 19);
            q.y = __builtin_bit_cast(uint32_t, evals[e] * INVK);
            tmp[(size_t)b * BCAP2 + off] = q;
        }
    }
}

// ---------------- sort pass B: within-bucket row sort ----------------------
__global__ __launch_bounds__(256) void k_sortB(const uint2* __restrict__ tmp,
                                               const uint32_t* __restrict__ bcnt,
                                               uint2* __restrict__ cv,
                                               uint32_t* __restrict__ rowstart,
                                               uint32_t* __restrict__ rowend) {
    __shared__ uint32_t hist[1280];
    __shared__ uint32_t tsum[256];
    int b = blockIdx.x;
    int t = threadIdx.x;
    uint32_t cnt = min(bcnt[b], (uint32_t)BCAP2);
    for (int i = t; i < 1280; i += 256) hist[i] = 0u;
    __syncthreads();
    const uint2* src = tmp + (size_t)b * BCAP2;
    for (uint32_t i = t; i < cnt; i += 256)
        atomicAdd(&hist[src[i].x >> 19], 1u);
    __syncthreads();
    uint32_t l[5];
    uint32_t s = 0u;
#pragma unroll
    for (int i = 0; i < 5; ++i) { l[i] = hist[t * 5 + i]; s += l[i]; }
    tsum[t] = s;
    __syncthreads();
    for (int off = 1; off < 256; off <<= 1) {
        uint32_t y = (t >= off) ? tsum[t - off] : 0u;
        __syncthreads();
        tsum[t] += y;
        __syncthreads();
    }
    uint32_t run = tsum[t] - s;
    uint32_t cvb = (uint32_t)b * BCAP2;
#pragma unroll
    for (int i = 0; i < 5; ++i) {
        uint32_t e0 = run;
        run += l[i];
        int idx = t * 5 + i;
        int row = b * BROWS + idx;
        if (idx < BROWS && row < N_NODES) {
            rowstart[row] = cvb + e0;
            rowend[row]   = cvb + run;
        }
        hist[idx] = e0;
    }
    __syncthreads();
    for (uint32_t i = t; i < cnt; i += 256) {
        uint2 p = src[i];
        uint32_t rl = p.x >> 19;
        uint32_t pos = atomicAdd(&hist[rl], 1u);
        uint2 q;
        q.x = p.x & 0x7FFFFu;
        q.y = p.y;
        cv[(size_t)cvb + pos] = q;
    }
}

// -------- SPMV: 2 adjacent rows per wave, fp8 gather, 8-deep bursts -------
__global__ __launch_bounds__(256) void k_spmv(const uint8_t* __restrict__ ego8,
                                              uint16_t* __restrict__ side,
                                              const uint32_t* __restrict__ rowstart,
                                              const uint32_t* __restrict__ rowend,
                                              const uint2* __restrict__ cv) {
    int lane = threadIdx.x & 63;
    int wv = __builtin_amdgcn_readfirstlane((int)((blockIdx.x * 256 + threadIdx.x) >> 6));
    int nw = (gridDim.x * 256) >> 6;
    for (int n0 = wv * 2; n0 < N_NODES; n0 += nw * 2) {
        uint32_t st  = __builtin_amdgcn_readfirstlane(rowstart[n0]);
        uint32_t mid = __builtin_amdgcn_readfirstlane(rowend[n0]);
        uint32_t en  = __builtin_amdgcn_readfirstlane(rowend[n0 + 1]);
        float acc0 = 0.0f, acc1 = 0.0f;
        for (uint32_t j0 = st; j0 < en; j0 += 8) {
            uint32_t cx[8];
            float v0[8], v1[8];
#pragma unroll
            for (int u = 0; u < 8; ++u) {
                uint2 p = cv[j0 + u];            // uniform addr -> scalar load
                uint32_t idx = j0 + (uint32_t)u;
                bool ok = idx < en;
                bool r1 = idx >= mid;
                cx[u] = ok ? p.x : 0u;
                float v = ok ? __builtin_bit_cast(float, p.y) : 0.0f;
                v0[u] = r1 ? 0.0f : v;           // uniform selects (SALU)
                v1[u] = r1 ? v : 0.0f;
            }
            float g[8];
#pragma unroll
            for (int u = 0; u < 8; ++u)
                g[u] = fp82f((uint32_t)ego8[(size_t)cx[u] * 64u + (uint32_t)lane]);
#pragma unroll
            for (int u = 0; u < 8; ++u) {
                acc0 = fmaf(v0[u], g[u], acc0);
                acc1 = fmaf(v1[u], g[u], acc1);
            }
        }
        side[(size_t)n0 * 64 + lane] = f2bf(acc0);
        side[(size_t)(n0 + 1) * 64 + lane] = f2bf(acc1);
    }
}

// -------- elementwise bf16 product frag: (side ∘ ego) --------
__device__ inline short8 mul_frag(short8 s, uint4 e) {
    uint32_t ew[4] = {e.x, e.y, e.z, e.w};
    short8 r;
#pragma unroll
    for (int i = 0; i < 4; ++i) {
        float a0 = bf2f((uint16_t)s[2 * i])     * bf2f((uint16_t)(ew[i] & 0xffffu));
        float a1 = bf2f((uint16_t)s[2 * i + 1]) * bf2f((uint16_t)(ew[i] >> 16));
        r[2 * i]     = (short)f2bf(a0);
        r[2 * i + 1] = (short)f2bf(a1);
    }
    return r;
}

// -------- dense via MFMA: [s | ego*s] (Nx128) @ [Wg;Wb] (128x64), in-place --
// bf16-only epilogue (fp8 sidecar is regenerated by k_repack).
__global__ __launch_bounds__(256) void k_dense_mfma(
        uint16_t* __restrict__ ego, const uint16_t* __restrict__ side,
        const float* __restrict__ Wg, const float* __restrict__ bg,
        const float* __restrict__ Wb, const float* __restrict__ bb,
        uint32_t km0, uint32_t km1) {
    int lane = threadIdx.x & 63;
    int wave = (blockIdx.x * 256 + threadIdx.x) >> 6;
    int nw = (gridDim.x * 256) >> 6;
    int m = lane & 15;     // A row within tile / C col within tile
    int g = lane >> 4;     // k-group (A) / row-group (C)

    short8 bfr[4][4];
#pragma unroll
    for (int kk = 0; kk < 4; ++kk) {
        const float* W = (kk < 2) ? Wg : Wb;
        int krow = (kk & 1) * 32 + 8 * g;
#pragma unroll
        for (int nt = 0; nt < 4; ++nt) {
#pragma unroll
            for (int i = 0; i < 8; ++i)
                bfr[kk][nt][i] = (short)f2bf(W[(krow + i) * 64 + 16 * nt + m]);
        }
    }
    float bias[4];
#pragma unroll
    for (int nt = 0; nt < 4; ++nt)
        bias[nt] = bg[16 * nt + m] + bb[16 * nt + m];

    for (int tile = wave; tile < HALF_N / 16; tile += nw) {
        int n0 = tile * 16;
        uint32_t keepB = 0;
        {
            const uint16_t* srow = side + (size_t)(n0 + m) * 64;
            const uint16_t* erw  = ego  + (size_t)(n0 + m) * 64;
            short8 a0 = *(const short8*)(srow + 8 * g);
            short8 a1 = *(const short8*)(srow + 32 + 8 * g);
            uint4  e0 = *(const uint4*)(erw + 8 * g);
            uint4  e1 = *(const uint4*)(erw + 32 + 8 * g);
            short8 a2 = mul_frag(a0, e0);
            short8 a3 = mul_frag(a1, e1);
            f32x4 acc[4];
#pragma unroll
            for (int nt = 0; nt < 4; ++nt) {
                acc[nt] = (f32x4)(0.0f);
                acc[nt] = __builtin_amdgcn_mfma_f32_16x16x32_bf16(a0, bfr[0][nt], acc[nt], 0, 0, 0);
                acc[nt] = __builtin_amdgcn_mfma_f32_16x16x32_bf16(a1, bfr[1][nt], acc[nt], 0, 0, 0);
                acc[nt] = __builtin_amdgcn_mfma_f32_16x16x32_bf16(a2, bfr[2][nt], acc[nt], 0, 0, 0);
                acc[nt] = __builtin_amdgcn_mfma_f32_16x16x32_bf16(a3, bfr[3][nt], acc[nt], 0, 0, 0);
            }
#pragma unroll
            for (int nt = 0; nt < 4; ++nt) {
#pragma unroll
                for (int i = 0; i < 4; ++i) {
                    int row = n0 + g * 4 + i;
                    int col = 16 * nt + m;
                    float h = acc[nt][i] + bias[nt];
                    h = (h >= 0.0f) ? h : 0.2f * h;
                    uint32_t j = (uint32_t)row * 64u + (uint32_t)col;
                    uint32_t o0, o1;
                    threefry2x32(km0, km1, j, j + HALF_MSG, o0, o1);
                    bool kA = tf_uniform(o0) < 0.9f;
                    keepB |= (uint32_t)(tf_uniform(o1) < 0.9f) << (nt * 4 + i);
                    ego[(size_t)row * 64 + col] = f2bf(kA ? h * INVK : 0.0f);
                }
            }
        }
        {
            int R = n0 + HALF_N;
            const uint16_t* srow = side + (size_t)(R + m) * 64;
            const uint16_t* erw  = ego  + (size_t)(R + m) * 64;
            short8 a0 = *(const short8*)(srow + 8 * g);
            short8 a1 = *(const short8*)(srow + 32 + 8 * g);
            uint4  e0 = *(const uint4*)(erw + 8 * g);
            uint4  e1 = *(const uint4*)(erw + 32 + 8 * g);
            short8 a2 = mul_frag(a0, e0);
            short8 a3 = mul_frag(a1, e1);
            f32x4 acc[4];
#pragma unroll
            for (int nt = 0; nt < 4; ++nt) {
                acc[nt] = (f32x4)(0.0f);
                acc[nt] = __builtin_amdgcn_mfma_f32_16x16x32_bf16(a0, bfr[0][nt], acc[nt], 0, 0, 0);
                acc[nt] = __builtin_amdgcn_mfma_f32_16x16x32_bf16(a1, bfr[1][nt], acc[nt], 0, 0, 0);
                acc[nt] = __builtin_amdgcn_mfma_f32_16x16x32_bf16(a2, bfr[2][nt], acc[nt], 0, 0, 0);
                acc[nt] = __builtin_amdgcn_mfma_f32_16x16x32_bf16(a3, bfr[3][nt], acc[nt], 0, 0, 0);
            }
#pragma unroll
            for (int nt = 0; nt < 4; ++nt) {
#pragma unroll
                for (int i = 0; i < 4; ++i) {
                    int row = R + g * 4 + i;
                    int col = 16 * nt + m;
                    float h = acc[nt][i] + bias[nt];
                    h = (h >= 0.0f) ? h : 0.2f * h;
                    bool kB = (keepB >> (nt * 4 + i)) & 1u;
                    ego[(size_t)row * 64 + col] = f2bf(kB ? h * INVK : 0.0f);
                }
            }
        }
    }
}

// ---------------- batch accumulation & finalize ----------------
__device__ inline float wred64(float v) {
#pragma unroll
    for (int m = 32; m >= 1; m >>= 1) v += __shfl_xor(v, m, 64);
    return v;
}

__global__ __launch_bounds__(256) void k_segacc(const void* __restrict__ ua_,
                                                const void* __restrict__ ia_,
                                                const int* __restrict__ uid,
                                                const int* __restrict__ iid,
                                                const int* __restrict__ nid,
                                                float* __restrict__ dotp,
                                                float* __restrict__ dotn,
                                                float* __restrict__ sqs,
                                                int normalize, int f32) {
    int gt = blockIdx.x * 256 + threadIdx.x;
    int w = gt >> 6, lane = gt & 63;
    if (w >= BATCH) return;
    int u = uid[w], p = iid[w], n = nid[w];
    float eu, ep, en;
    if (f32) {
        const float* ua = (const float*)ua_;
        const float* ia = (const float*)ia_;
        eu = ua[(size_t)u * EMB + lane];
        ep = ia[(size_t)p * EMB + lane];
        en = ia[(size_t)n * EMB + lane];
    } else {
        const uint16_t* ua = (const uint16_t*)ua_;
        const uint16_t* ia = (const uint16_t*)ia_;
        eu = bf2f(ua[(size_t)u * EMB + lane]);
        ep = bf2f(ia[(size_t)p * EMB + lane]);
        en = bf2f(ia[(size_t)n * EMB + lane]);
    }
    if (normalize) {
        float su = wred64(eu * eu);
        float sp = wred64(ep * ep);
        float sn = wred64(en * en);
        eu /= fmaxf(sqrtf(su), 1e-12f);
        ep /= fmaxf(sqrtf(sp), 1e-12f);
        en /= fmaxf(sqrtf(sn), 1e-12f);
    }
    float dp = wred64(eu * ep);
    float dn = wred64(eu * en);
    float s3 = wred64(eu * eu + ep * ep + en * en);
    if (lane == 0) {
        dotp[w] += dp;
        dotn[w] += dn;
        sqs[w]  += s3;
    }
}

__global__ __launch_bounds__(256) void k_finalize(const float* __restrict__ dotp,
                                                  const float* __restrict__ dotn,
                                                  const float* __restrict__ sqs,
                                                  float* __restrict__ out) {
    __shared__ float smf[256], ssq[256];
    int t = threadIdx.x;
    float mf = 0.0f, s = 0.0f;
    for (int b = t; b < BATCH; b += 256) {
        float x = dotp[b] - dotn[b];
        float ls = fminf(x, 0.0f) - log1pf(expf(-fabsf(x)));
        mf += ls;
        s += sqs[b];
    }
    smf[t] = mf; ssq[t] = s;
    __syncthreads();
    for (int off = 128; off > 0; off >>= 1) {
        if (t < off) { smf[t] += smf[t + off]; ssq[t] += ssq[t + off]; }
        __syncthreads();
    }
    if (t == 0) {
        float mf_loss = -smf[0] / (float)BATCH;
        float reg = 0.5f * ssq[0];
        float emb_loss = (float)1e-4 * reg / (float)BATCH;
        out[0] = mf_loss + emb_loss;
        out[1] = mf_loss;
        out[2] = emb_loss;
    }
}

// ---------------- launch ----------------
extern "C" void kernel_launch(void* const* d_in, const int* in_sizes, int n_in,
                              void* d_out, int out_size, void* d_ws, size_t ws_size,
                              hipStream_t stream) {
    const int*   erow  = (const int*)d_in[0];
    const int*   ecol  = (const int*)d_in[1];
    const float* evals = (const float*)d_in[2];
    const float* uemb  = (const float*)d_in[3];
    const float* iemb  = (const float*)d_in[4];
    const int*   uid   = (const int*)d_in[5];
    const int*   iid   = (const int*)d_in[6];
    const int*   nid   = (const int*)d_in[7];
    const float* Wg[3] = {(const float*)d_in[8],  (const float*)d_in[12], (const float*)d_in[16]};
    const float* bg[3] = {(const float*)d_in[9],  (const float*)d_in[13], (const float*)d_in[17]};
    const float* Wb[3] = {(const float*)d_in[10], (const float*)d_in[14], (const float*)d_in[18]};
    const float* bb[3] = {(const float*)d_in[11], (const float*)d_in[15], (const float*)d_in[19]};

    // workspace layout (~130 MB)
    const size_t NBE = (size_t)NBK2 * BCAP2;                        // 1,966,080
    uint2*    tmp      = (uint2*)d_ws;                              // 15.7 MB
    uint2*    cv       = tmp + NBE;                                 // 15.7 MB (+8 pad)
    uint16_t* side     = (uint16_t*)(cv + NBE + 8);                 // 38.4 MB
    uint16_t* ego      = side + (size_t)N_NODES * EMB;              // 38.4 MB
    uint8_t*  ego8     = (uint8_t*)(ego + (size_t)N_NODES * EMB);   // 19.2 MB
    uint32_t* rowstart = (uint32_t*)(ego8 + (size_t)N_NODES * EMB); // 1.2 MB
    uint32_t* rowend   = rowstart + N_NODES;                        // 1.2 MB
    uint32_t* bcnt     = rowend + N_NODES;                          // 1 KB
    float*    dotp     = (float*)(bcnt + NBK2);                     // 16 KB
    float*    dotn     = dotp + BATCH;
    float*    sqs      = dotn + BATCH;
    size_t needed = (NBE * 2 + 8) * 8 + (size_t)N_NODES * EMB * (2 * 2 + 1)
                  + ((size_t)2 * N_NODES + NBK2 + 3 * BATCH) * 4;
    if (ws_size < needed) return;

    // host-side JAX key derivation: key(42) = (0,42)
    uint32_t a0, b0, a1, b1;
    threefry2x32(0u, 42u, 0u, 2u, a0, b0);   // split block 0
    threefry2x32(0u, 42u, 1u, 3u, a1, b1);   // split block 1
    uint32_t knode0 = a0, knode1 = a1;       // k_node
    uint32_t kmsg0  = b0, kmsg1  = b1;       // k_msg
    uint32_t mk[6];
    for (uint32_t k = 0; k < 3; ++k)
        threefry2x32(kmsg0, kmsg1, 0u, k, mk[2 * k], mk[2 * k + 1]);

    hipMemsetAsync(bcnt, 0, (size_t)NBK2 * 4, stream);
    hipMemsetAsync(dotp, 0, 3 * BATCH * 4, stream);

    // ego (bf16 + fp8) init + two-pass LDS-binned CSR build
    k_conv<<<(N_NODES * EMB / 4 + 255) / 256, 256, 0, stream>>>(uemb, iemb, ego, ego8);
    k_sortA<<<ABLK, 256, 0, stream>>>(erow, ecol, evals, bcnt, tmp, knode0, knode1);
    k_sortB<<<NBK2, 256, 0, stream>>>(tmp, bcnt, cv, rowstart, rowend);

    // segment 0: raw initial embeddings (fp32, exact)
    k_segacc<<<BATCH * 64 / 256, 256, 0, stream>>>(uemb, iemb, uid, iid, nid,
                                                   dotp, dotn, sqs, 0, 1);

    for (int k = 0; k < 3; ++k) {
        k_spmv<<<2048, 256, 0, stream>>>(ego8, side, rowstart, rowend, cv);
        k_dense_mfma<<<768, 256, 0, stream>>>(ego, side, Wg[k], bg[k], Wb[k], bb[k],
                                              mk[2 * k], mk[2 * k + 1]);
        if (k < 2)
            k_repack<<<(N_NODES * EMB / 8 + 255) / 256, 256, 0, stream>>>(ego, ego8);
        k_segacc<<<BATCH * 64 / 256, 256, 0, stream>>>(ego, ego + (size_t)USER_NUM * EMB,
                                                       uid, iid, nid, dotp, dotn, sqs, 1, 0);
    }
    k_finalize<<<1, 256, 0, stream>>>(dotp, dotn, sqs, (float*)d_out);
}